// Round 16
// baseline (64.653 us; speedup 1.0000x reference)
//
#include <hip/hip_runtime.h>
#include <hip/hip_bf16.h>
#include <math.h>

#define NN 8192
#define EE 128

static constexpr float INV_T = 1.0f / 0.07f;
static constexpr float LOG2E = 1.4426950408889634f;
static constexpr float LN2   = 0.6931471805599453f;
static constexpr float SENT  = -3.0e38f;

typedef __attribute__((ext_vector_type(8))) short fragAB;   // 8 bf16
typedef __attribute__((ext_vector_type(4))) float f32x4;
typedef const __attribute__((address_space(1))) void gvoid;
typedef __attribute__((address_space(3))) void lvoid;

__device__ inline float fexp2(float x) { float r; asm("v_exp_f32 %0, %1" : "=v"(r) : "v"(x)); return r; }
__device__ inline float flog2(float x) { float r; asm("v_log_f32 %0, %1" : "=v"(r) : "v"(x)); return r; }

template<int CTRL>
__device__ inline float dpp_f(float x) {
  return __builtin_bit_cast(float,
      __builtin_amdgcn_update_dpp(0, __builtin_bit_cast(int, x), CTRL, 0xf, 0xf, true));
}
__device__ inline float red16_max(float x) {
  x = fmaxf(x, dpp_f<0xB1>(x));    // quad_perm [1,0,3,2]
  x = fmaxf(x, dpp_f<0x4E>(x));    // quad_perm [2,3,0,1]
  x = fmaxf(x, dpp_f<0x141>(x));   // row_half_mirror
  x = fmaxf(x, dpp_f<0x140>(x));   // row_mirror
  return x;
}
__device__ inline float red16_add(float x) {
  x += dpp_f<0xB1>(x); x += dpp_f<0x4E>(x); x += dpp_f<0x141>(x); x += dpp_f<0x140>(x);
  return x;
}

__device__ inline ushort f32_to_bf16_bits(float x) {
  union { float f; unsigned u; } c; c.f = x;
  unsigned u = c.u;
  u += 0x7fffu + ((u >> 16) & 1u);   // RNE
  return (ushort)(u >> 16);
}

// fp32 -> bf16 (A pre-scaled by 1/temp*log2e so scores are log2-domain),
// plus exact fp32 diagonal dot products (log2 units).
__global__ void lsl_cvt_kernel(const float* __restrict__ A, const float* __restrict__ T,
                               ushort* __restrict__ Ab, ushort* __restrict__ Tb,
                               float* __restrict__ diag) {
  const int t = blockIdx.x * 256 + threadIdx.x;
  const int i = t * 4;
  float4 a = *reinterpret_cast<const float4*>(A + i);
  float4 tt = *reinterpret_cast<const float4*>(T + i);
  ushort4 oa, ot;
  const float SC = INV_T * LOG2E;
  oa.x = f32_to_bf16_bits(a.x * SC); oa.y = f32_to_bf16_bits(a.y * SC);
  oa.z = f32_to_bf16_bits(a.z * SC); oa.w = f32_to_bf16_bits(a.w * SC);
  ot.x = f32_to_bf16_bits(tt.x); ot.y = f32_to_bf16_bits(tt.y);
  ot.z = f32_to_bf16_bits(tt.z); ot.w = f32_to_bf16_bits(tt.w);
  *reinterpret_cast<ushort4*>(Ab + i) = oa;
  *reinterpret_cast<ushort4*>(Tb + i) = ot;

  float pd = a.x * tt.x + a.y * tt.y + a.z * tt.z + a.w * tt.w;
  pd += __shfl_xor(pd, 1); pd += __shfl_xor(pd, 2); pd += __shfl_xor(pd, 4);
  pd += __shfl_xor(pd, 8); pd += __shfl_xor(pd, 16);
  if ((threadIdx.x & 31) == 0) diag[i >> 7] = pd * (INV_T * LOG2E);   // log2 units
}

// WG = one 128-row band x TWO 128-col tiles, processed as 4 stages of 64
// cols. 512 threads = 8 waves, each 16 rows x 64 cols per stage. LDS diet:
// As 32KB (staged once) + Bs 16KB (half-tile, re-staged per stage, fetch
// hidden under the previous stage's epilogue) + cscr 4KB = 52KB -> 3 WGs/CU
// (vs 2 at 64KB) for independently-phased barrier overlap. XOR-swizzled LDS
// (linear dest + pre-swizzled global source, same XOR on read). Col partials
// 8-way combined via cscr into 128-row blocks (colp = 64 blocks). Cross-lane
// strictly __shfl_xor/DPP (same-operand permlane32_swap is UNSOUND - R11/R14).
__global__ __launch_bounds__(512, 6) void
lsl_tile_kernel(const ushort* __restrict__ Ab, const ushort* __restrict__ Tb,
                const int* __restrict__ fids,
                float2* __restrict__ rowp, float2* __restrict__ colp) {
  __shared__ ushort As[128 * 128];   // 32 KB
  __shared__ ushort Bs[64 * 128];    // 16 KB
  __shared__ float2 cscr[8 * 64];    // 4 KB

  const int bid = blockIdx.x;
  const int swz = (bid & 7) * 256 + (bid >> 3);   // bijective XCD chunking (2048 WGs)
  const int tm = swz >> 5, tnq = swz & 31;
  const int tid = threadIdx.x;
  const int lane = tid & 63;
  const int wid  = tid >> 6;          // 0..7 (16-row band within the 128 rows)
  const int rbase = tm * 128 + wid * 16;
  const int lr = lane & 15, lg = lane >> 4;

  // staging geometry (shared by A and all B half-tiles)
  const int trow = tid >> 4;                       // 0..31
  const int scol = ((tid & 15) ^ (trow & 15)) * 8;

  auto stageB = [&](int tn, int h) {
    const ushort* gB = Tb + (size_t)(tn * 128 + h * 64 + trow) * EE + scol;
#pragma unroll
    for (int i = 0; i < 2; ++i)
      __builtin_amdgcn_global_load_lds((gvoid*)(gB + (size_t)i * 32 * EE),
          (lvoid*)((char*)Bs + i * 8192 + wid * 1024), 16, 0, 0);
  };

  // ---- stage A (shared across all 4 stages) + B(first half-tile) ----
  {
    const ushort* gA = Ab + (size_t)(tm * 128 + trow) * EE + scol;
#pragma unroll
    for (int i = 0; i < 4; ++i)
      __builtin_amdgcn_global_load_lds((gvoid*)(gA + (size_t)i * 32 * EE),
          (lvoid*)((char*)As + i * 8192 + wid * 1024), 16, 0, 0);
  }
  stageB(tnq * 2, 0);

  // row fids (4 rows per lane-group; shared by all stages)
  int fr[4];
  {
    int4 v4 = *reinterpret_cast<const int4*>(fids + rbase + lg * 4);
    fr[0] = v4.x; fr[1] = v4.y; fr[2] = v4.z; fr[3] = v4.w;
  }

  __syncthreads();   // A + B(first) staged

#pragma unroll
  for (int s = 0; s < 4; ++s) {
    const int q = s >> 1, h = s & 1;
    const int tn = tnq * 2 + q;
    const int cbase = tn * 128 + h * 64;

    // ---- compute: 16 rows x 64 cols (4 ks x 4 fn MFMA) ----
    f32x4 acc[4] = {};   // [fn]; D: col = lane&15, row = (lane>>4)*4 + r
#pragma unroll
    for (int ks = 0; ks < 4; ++ks) {
      fragAB av, bv[4];
      av = *reinterpret_cast<const fragAB*>(
          &As[(wid * 16 + lr) * 128 + (((ks * 4 + lg) ^ lr) * 8)]);
#pragma unroll
      for (int f = 0; f < 4; ++f)
        bv[f] = *reinterpret_cast<const fragAB*>(
            &Bs[(f * 16 + lr) * 128 + (((ks * 4 + lg) ^ lr) * 8)]);
#pragma unroll
      for (int fn = 0; fn < 4; ++fn)
        acc[fn] = __builtin_amdgcn_mfma_f32_16x16x32_bf16(av, bv[fn], acc[fn], 0, 0, 0);
    }

    __syncthreads();   // B1: all waves done reading Bs

    if (s < 3) stageB(tnq * 2 + ((s + 1) >> 1), (s + 1) & 1);  // hides under epilogue

    // col fids
    int fc[4];
#pragma unroll
    for (int fn = 0; fn < 4; ++fn) fc[fn] = fids[cbase + fn * 16 + lr];

    // read-once sweep: acc -> masked VGPR copies.
    // diag crosses this 16x64 sub-tile iff tm==tn and (wid>>2)==h; then
    // row==col <=> fn == (wid&3) and lr == lg*4+r.
    float e[4][4];
    const bool dt = (tm == tn) && ((wid >> 2) == h);
    const int dfn = wid & 3;
#pragma unroll
    for (int fn = 0; fn < 4; ++fn)
#pragma unroll
      for (int r = 0; r < 4; ++r) {
        float v = acc[fn][r];
        bool keep = (fr[r] != fc[fn]) || (dt && fn == dfn && lr == lg * 4 + r);
        e[fn][r] = keep ? v : SENT;
      }

    // ---- row pass (row fixed by (lg,r); 64 cols = 4 fn x 16 lr) ----
    float rm[4], rs[4];
#pragma unroll
    for (int r = 0; r < 4; ++r)
      rm[r] = fmaxf(fmaxf(e[0][r], e[1][r]), fmaxf(e[2][r], e[3][r]));
#pragma unroll
    for (int r = 0; r < 4; ++r) rm[r] = red16_max(rm[r]);
#pragma unroll
    for (int r = 0; r < 4; ++r)
      rs[r] = (fexp2(e[0][r] - rm[r]) + fexp2(e[1][r] - rm[r]))
            + (fexp2(e[2][r] - rm[r]) + fexp2(e[3][r] - rm[r]));
#pragma unroll
    for (int r = 0; r < 4; ++r) rs[r] = red16_add(rs[r]);

    const int rblk = tn * 2 + h;
    if (lr == 0) {
#pragma unroll
      for (int r = 0; r < 4; ++r)
        rowp[(size_t)rblk * NN + (rbase + lg * 4 + r)] = make_float2(rm[r], rs[r]);
    }

    // ---- col pass over this wave's 16 rows ----
    float cm[4], cs[4];
#pragma unroll
    for (int fn = 0; fn < 4; ++fn)
      cm[fn] = fmaxf(fmaxf(e[fn][0], e[fn][1]), fmaxf(e[fn][2], e[fn][3]));
    {
      float t0 = __shfl_xor(cm[0], 16), t1 = __shfl_xor(cm[1], 16),
            t2 = __shfl_xor(cm[2], 16), t3 = __shfl_xor(cm[3], 16);
      cm[0] = fmaxf(cm[0], t0); cm[1] = fmaxf(cm[1], t1);
      cm[2] = fmaxf(cm[2], t2); cm[3] = fmaxf(cm[3], t3);
      t0 = __shfl_xor(cm[0], 32); t1 = __shfl_xor(cm[1], 32);
      t2 = __shfl_xor(cm[2], 32); t3 = __shfl_xor(cm[3], 32);
      cm[0] = fmaxf(cm[0], t0); cm[1] = fmaxf(cm[1], t1);
      cm[2] = fmaxf(cm[2], t2); cm[3] = fmaxf(cm[3], t3);
    }
#pragma unroll
    for (int fn = 0; fn < 4; ++fn)
      cs[fn] = (fexp2(e[fn][0] - cm[fn]) + fexp2(e[fn][1] - cm[fn]))
             + (fexp2(e[fn][2] - cm[fn]) + fexp2(e[fn][3] - cm[fn]));
    {
      float t0 = __shfl_xor(cs[0], 16), t1 = __shfl_xor(cs[1], 16),
            t2 = __shfl_xor(cs[2], 16), t3 = __shfl_xor(cs[3], 16);
      cs[0] += t0; cs[1] += t1; cs[2] += t2; cs[3] += t3;
      t0 = __shfl_xor(cs[0], 32); t1 = __shfl_xor(cs[1], 32);
      t2 = __shfl_xor(cs[2], 32); t3 = __shfl_xor(cs[3], 32);
      cs[0] += t0; cs[1] += t1; cs[2] += t2; cs[3] += t3;
    }

    // each wave publishes its 16-row col partials (64 cols)
    if (lg == 0) {
#pragma unroll
      for (int fn = 0; fn < 4; ++fn)
        cscr[wid * 64 + fn * 16 + lr] = make_float2(cm[fn], cs[fn]);
    }

    __syncthreads();   // B2: cscr complete; next Bs landed (vmcnt drained)

    // 8-way combine -> one 128-row colp block; wave wid owns cols [wid*8, +8).
    // (cscr reuse is safe without a third barrier: every combine-read precedes
    //  this wave's next B1; every next-stage cscr-write follows it.)
    if (lane < 8) {
      const int c = wid * 8 + lane;
      float M = cscr[c].x;
#pragma unroll
      for (int w = 1; w < 8; ++w) M = fmaxf(M, cscr[w * 64 + c].x);
      float S = 0.f;
#pragma unroll
      for (int w = 0; w < 8; ++w) {
        float2 p = cscr[w * 64 + c];
        S += p.y * fexp2(p.x - M);
      }
      colp[(size_t)tm * NN + (cbase + c)] = make_float2(M, S);
    }
  }
}

// WG handles 32 samples: stage [blocks][32 samples] slab through padded LDS
// (coalesced), 8 threads per sample. Pass 0: 128 row-partial blocks; pass 1:
// 64 col-partial blocks (128-row granularity).
__global__ __launch_bounds__(256) void
lsl_merge_kernel(const float2* __restrict__ rowp, const float2* __restrict__ colp,
                 const float* __restrict__ diag, float* __restrict__ bsum) {
  __shared__ float2 sl[128 * 33];
  __shared__ float2 red[32][8];
  const int tid = threadIdx.x;
  const int ibase = blockIdx.x * 32;
  const int s = tid & 31, p = tid >> 5;

  float lse0 = 0.f, lse1 = 0.f;
  for (int pass = 0; pass < 2; ++pass) {
    const float2* __restrict__ src = pass ? colp : rowp;
    const int NB = pass ? 64 : 128;
    const int PB = NB >> 3;
    for (int k = 0; k < (NB >> 3); ++k) {
      int L = tid + k * 256;
      int b = L >> 5, di = L & 31;
      sl[b * 33 + di] = src[(size_t)b * NN + ibase + di];
    }
    __syncthreads();
    float m = SENT;
    for (int k = 0; k < PB; ++k) m = fmaxf(m, sl[(p * PB + k) * 33 + s].x);
    float sum = 0.f;
    for (int k = 0; k < PB; ++k) {
      float2 v = sl[(p * PB + k) * 33 + s];
      sum += v.y * fexp2(v.x - m);
    }
    red[s][p] = make_float2(m, sum);
    __syncthreads();
    if (p == 0) {
      float M = SENT;
#pragma unroll
      for (int k = 0; k < 8; ++k) M = fmaxf(M, red[s][k].x);
      float S = 0.f;
#pragma unroll
      for (int k = 0; k < 8; ++k) S += red[s][k].y * fexp2(red[s][k].x - M);
      if (pass == 0) lse0 = M + flog2(S); else lse1 = M + flog2(S);
    }
    __syncthreads();
  }

  if (tid < 32) {
    float loss = lse0 + lse1 - 2.f * diag[ibase + tid];   // log2 units
#pragma unroll
    for (int d = 1; d < 32; d <<= 1) loss += __shfl_xor(loss, d);
    if (tid == 0) bsum[blockIdx.x] = loss;
  }
}

__global__ __launch_bounds__(256) void
lsl_final_kernel(const float* __restrict__ bsum, float* __restrict__ out) {
  float v = bsum[threadIdx.x];
#pragma unroll
  for (int d = 1; d < 64; d <<= 1) v += __shfl_xor(v, d);
  __shared__ float l4[4];
  if ((threadIdx.x & 63) == 0) l4[threadIdx.x >> 6] = v;
  __syncthreads();
  if (threadIdx.x == 0) out[0] = (l4[0] + l4[1] + l4[2] + l4[3]) * (LN2 / (float)NN);
}

extern "C" void kernel_launch(void* const* d_in, const int* in_sizes, int n_in,
                              void* d_out, int out_size, void* d_ws, size_t ws_size,
                              hipStream_t stream) {
  const float* A = (const float*)d_in[0];
  const float* T = (const float*)d_in[1];
  const int* fids = (const int*)d_in[2];
  float* out = (float*)d_out;
  char* ws = (char*)d_ws;

  // ws: Ab 2MB | Tb 2MB | diag 32KB | rowp 8MB | colp 4MB | bsum 1KB
  size_t off = 0;
  ushort* Ab  = (ushort*)(ws + off); off += (size_t)NN * EE * 2;
  ushort* Tb  = (ushort*)(ws + off); off += (size_t)NN * EE * 2;
  float* diag = (float*)(ws + off);  off += (size_t)NN * 4;
  float2* rowp = (float2*)(ws + off); off += (size_t)NN * 128 * 8;
  float2* colp = (float2*)(ws + off); off += (size_t)NN * 64 * 8;
  float* bsum = (float*)(ws + off);  off += 1024;

  hipLaunchKernelGGL(lsl_cvt_kernel, dim3(NN * EE / 4 / 256), dim3(256), 0, stream, A, T, Ab, Tb, diag);
  hipLaunchKernelGGL(lsl_tile_kernel, dim3(2048), dim3(512), 0, stream, Ab, Tb, fids, rowp, colp);
  hipLaunchKernelGGL(lsl_merge_kernel, dim3(NN / 32), dim3(256), 0, stream, rowp, colp, diag, bsum);
  hipLaunchKernelGGL(lsl_final_kernel, dim3(1), dim3(256), 0, stream, bsum, out);
}

// Round 18
// 61.721 us; speedup vs baseline: 1.0475x; 1.0475x over previous
//
#include <hip/hip_runtime.h>
#include <hip/hip_bf16.h>
#include <math.h>

#define NN 8192
#define EE 128

static constexpr float INV_T = 1.0f / 0.07f;
static constexpr float LOG2E = 1.4426950408889634f;
static constexpr float LN2   = 0.6931471805599453f;
static constexpr float SENT  = -3.0e38f;

typedef __attribute__((ext_vector_type(8))) short fragAB;   // 8 bf16
typedef __attribute__((ext_vector_type(4))) float f32x4;
typedef const __attribute__((address_space(1))) void gvoid;
typedef __attribute__((address_space(3))) void lvoid;

__device__ inline float fexp2(float x) { float r; asm("v_exp_f32 %0, %1" : "=v"(r) : "v"(x)); return r; }
__device__ inline float flog2(float x) { float r; asm("v_log_f32 %0, %1" : "=v"(r) : "v"(x)); return r; }

template<int CTRL>
__device__ inline float dpp_f(float x) {
  return __builtin_bit_cast(float,
      __builtin_amdgcn_update_dpp(0, __builtin_bit_cast(int, x), CTRL, 0xf, 0xf, true));
}
__device__ inline float red16_max(float x) {
  x = fmaxf(x, dpp_f<0xB1>(x));    // quad_perm [1,0,3,2]
  x = fmaxf(x, dpp_f<0x4E>(x));    // quad_perm [2,3,0,1]
  x = fmaxf(x, dpp_f<0x141>(x));   // row_half_mirror
  x = fmaxf(x, dpp_f<0x140>(x));   // row_mirror
  return x;
}
__device__ inline float red16_add(float x) {
  x += dpp_f<0xB1>(x); x += dpp_f<0x4E>(x); x += dpp_f<0x141>(x); x += dpp_f<0x140>(x);
  return x;
}

__device__ inline ushort f32_to_bf16_bits(float x) {
  union { float f; unsigned u; } c; c.f = x;
  unsigned u = c.u;
  u += 0x7fffu + ((u >> 16) & 1u);   // RNE
  return (ushort)(u >> 16);
}

// fp32 -> bf16 (A pre-scaled by 1/temp*log2e so scores are log2-domain),
// plus exact fp32 diagonal dot products (log2 units).
__global__ void lsl_cvt_kernel(const float* __restrict__ A, const float* __restrict__ T,
                               ushort* __restrict__ Ab, ushort* __restrict__ Tb,
                               float* __restrict__ diag) {
  const int t = blockIdx.x * 256 + threadIdx.x;
  const int i = t * 4;
  float4 a = *reinterpret_cast<const float4*>(A + i);
  float4 tt = *reinterpret_cast<const float4*>(T + i);
  ushort4 oa, ot;
  const float SC = INV_T * LOG2E;
  oa.x = f32_to_bf16_bits(a.x * SC); oa.y = f32_to_bf16_bits(a.y * SC);
  oa.z = f32_to_bf16_bits(a.z * SC); oa.w = f32_to_bf16_bits(a.w * SC);
  ot.x = f32_to_bf16_bits(tt.x); ot.y = f32_to_bf16_bits(tt.y);
  ot.z = f32_to_bf16_bits(tt.z); ot.w = f32_to_bf16_bits(tt.w);
  *reinterpret_cast<ushort4*>(Ab + i) = oa;
  *reinterpret_cast<ushort4*>(Tb + i) = ot;

  float pd = a.x * tt.x + a.y * tt.y + a.z * tt.z + a.w * tt.w;
  pd += __shfl_xor(pd, 1); pd += __shfl_xor(pd, 2); pd += __shfl_xor(pd, 4);
  pd += __shfl_xor(pd, 8); pd += __shfl_xor(pd, 16);
  if ((threadIdx.x & 31) == 0) diag[i >> 7] = pd * (INV_T * LOG2E);   // log2 units
}

// WG = one 128-row band x TWO adjacent 128-col tiles (tn = 2*tnp, 2*tnp+1).
// 512 threads = 8 waves in 4x2 (32 rows x 64 cols each per tile). A staged
// once; B single-buffered, re-staged for tile 2 with the gload_lds burst
// issued before tile 1's epilogue (staging hides under ~75% of the work).
// XOR-swizzled LDS (linear dest + pre-swizzled global source, same XOR on
// read). Col partials of wave pairs combined via dedicated cscr scratch.
// Cross-lane strictly __shfl_xor/DPP (permlane32_swap retired: 3 deterministic
// failures under distinct usage hypotheses — R11/R14/R17).
__global__ __launch_bounds__(512, 4) void
lsl_tile_kernel(const ushort* __restrict__ Ab, const ushort* __restrict__ Tb,
                const int* __restrict__ fids,
                float2* __restrict__ rowp, float2* __restrict__ colp) {
  __shared__ ushort As[128 * 128];
  __shared__ ushort Bs[128 * 128];
  __shared__ float2 cscr[4 * 64];

  const int bid = blockIdx.x;
  const int swz = (bid & 7) * 256 + (bid >> 3);   // bijective XCD chunking (2048 WGs)
  const int tm = swz >> 5, tnp = swz & 31;
  const int tid = threadIdx.x;
  const int lane = tid & 63;
  const int wid  = tid >> 6;          // 0..7
  const int wm = wid >> 1;            // 0..3 (32-row band)
  const int wn = wid & 1;             // 0..1 (64-col band)
  const int rbase = tm * 128 + wm * 32;
  const int lr = lane & 15, lg = lane >> 4;

  // staging geometry (shared by A and both B tiles)
  const int trow = tid >> 4;                       // 0..31
  const int scol = ((tid & 15) ^ (trow & 15)) * 8;

  // ---- stage A (shared) + B(tile 1) ----
  {
    const ushort* gA = Ab + (size_t)(tm * 128 + trow) * EE + scol;
    const ushort* gB = Tb + (size_t)(tnp * 256 + trow) * EE + scol;
#pragma unroll
    for (int i = 0; i < 4; ++i)
      __builtin_amdgcn_global_load_lds((gvoid*)(gA + (size_t)i * 32 * EE),
          (lvoid*)((char*)As + i * 8192 + wid * 1024), 16, 0, 0);
#pragma unroll
    for (int i = 0; i < 4; ++i)
      __builtin_amdgcn_global_load_lds((gvoid*)(gB + (size_t)i * 32 * EE),
          (lvoid*)((char*)Bs + i * 8192 + wid * 1024), 16, 0, 0);
  }

  // row fids (shared by both tiles)
  int fr[2][4];
#pragma unroll
  for (int fm = 0; fm < 2; ++fm) {
    int4 v4 = *reinterpret_cast<const int4*>(fids + rbase + fm * 16 + lg * 4);
    fr[fm][0] = v4.x; fr[fm][1] = v4.y; fr[fm][2] = v4.z; fr[fm][3] = v4.w;
  }

  // epilogue for one computed 32x64 sub-tile
  auto epilogue = [&](f32x4 (&acc)[2][4], int tn) {
    const int cbase = tn * 128 + wn * 64;
    int fc[4];
#pragma unroll
    for (int fn = 0; fn < 4; ++fn) fc[fn] = fids[cbase + fn * 16 + lr];

    // read-once sweep: acc -> masked VGPR copies. Diagonal crosses this
    // 32x64 sub-tile when tm==tn and (wm>>1)==wn; then row==col <=>
    // fn == (wm&1)*2+fm and lr == lg*4+r.
    float e[2][4][4];
    const bool dt = (tm == tn) && ((wm >> 1) == wn);
    const int dfb = (wm & 1) * 2;
#pragma unroll
    for (int fm = 0; fm < 2; ++fm)
#pragma unroll
      for (int fn = 0; fn < 4; ++fn)
#pragma unroll
        for (int r = 0; r < 4; ++r) {
          float v = acc[fm][fn][r];
          bool keep = (fr[fm][r] != fc[fn]) || (dt && fn == dfb + fm && lr == lg * 4 + r);
          e[fm][fn][r] = keep ? v : SENT;
        }

    // row pass, stage-major
    float rm[2][4];
#pragma unroll
    for (int fm = 0; fm < 2; ++fm)
#pragma unroll
      for (int r = 0; r < 4; ++r)
        rm[fm][r] = fmaxf(fmaxf(e[fm][0][r], e[fm][1][r]),
                          fmaxf(e[fm][2][r], e[fm][3][r]));
#pragma unroll
    for (int fm = 0; fm < 2; ++fm)
#pragma unroll
      for (int r = 0; r < 4; ++r)
        rm[fm][r] = red16_max(rm[fm][r]);

    float rs[2][4];
#pragma unroll
    for (int fm = 0; fm < 2; ++fm)
#pragma unroll
      for (int r = 0; r < 4; ++r)
        rs[fm][r] = (fexp2(e[fm][0][r] - rm[fm][r]) + fexp2(e[fm][1][r] - rm[fm][r]))
                  + (fexp2(e[fm][2][r] - rm[fm][r]) + fexp2(e[fm][3][r] - rm[fm][r]));
#pragma unroll
    for (int fm = 0; fm < 2; ++fm)
#pragma unroll
      for (int r = 0; r < 4; ++r)
        rs[fm][r] = red16_add(rs[fm][r]);

    const int rblk = tn * 2 + wn;
    if (lr == 0) {
#pragma unroll
      for (int fm = 0; fm < 2; ++fm)
#pragma unroll
        for (int r = 0; r < 4; ++r)
          rowp[(size_t)rblk * NN + (rbase + fm * 16 + lg * 4 + r)] = make_float2(rm[fm][r], rs[fm][r]);
    }

    // col pass over this wave's 32 rows
    float cm[4];
#pragma unroll
    for (int fn = 0; fn < 4; ++fn) {
      float m0 = fmaxf(fmaxf(e[0][fn][0], e[0][fn][1]), fmaxf(e[0][fn][2], e[0][fn][3]));
      float m1 = fmaxf(fmaxf(e[1][fn][0], e[1][fn][1]), fmaxf(e[1][fn][2], e[1][fn][3]));
      cm[fn] = fmaxf(m0, m1);
    }
    {
      float t0 = __shfl_xor(cm[0], 16), t1 = __shfl_xor(cm[1], 16),
            t2 = __shfl_xor(cm[2], 16), t3 = __shfl_xor(cm[3], 16);
      cm[0] = fmaxf(cm[0], t0); cm[1] = fmaxf(cm[1], t1);
      cm[2] = fmaxf(cm[2], t2); cm[3] = fmaxf(cm[3], t3);
      t0 = __shfl_xor(cm[0], 32); t1 = __shfl_xor(cm[1], 32);
      t2 = __shfl_xor(cm[2], 32); t3 = __shfl_xor(cm[3], 32);
      cm[0] = fmaxf(cm[0], t0); cm[1] = fmaxf(cm[1], t1);
      cm[2] = fmaxf(cm[2], t2); cm[3] = fmaxf(cm[3], t3);
    }
    float cs[4];
#pragma unroll
    for (int fn = 0; fn < 4; ++fn) {
      float s0 = (fexp2(e[0][fn][0] - cm[fn]) + fexp2(e[0][fn][1] - cm[fn]))
               + (fexp2(e[0][fn][2] - cm[fn]) + fexp2(e[0][fn][3] - cm[fn]));
      float s1 = (fexp2(e[1][fn][0] - cm[fn]) + fexp2(e[1][fn][1] - cm[fn]))
               + (fexp2(e[1][fn][2] - cm[fn]) + fexp2(e[1][fn][3] - cm[fn]));
      cs[fn] = s0 + s1;
    }
    {
      float t0 = __shfl_xor(cs[0], 16), t1 = __shfl_xor(cs[1], 16),
            t2 = __shfl_xor(cs[2], 16), t3 = __shfl_xor(cs[3], 16);
      cs[0] += t0; cs[1] += t1; cs[2] += t2; cs[3] += t3;
      t0 = __shfl_xor(cs[0], 32); t1 = __shfl_xor(cs[1], 32);
      t2 = __shfl_xor(cs[2], 32); t3 = __shfl_xor(cs[3], 32);
      cs[0] += t0; cs[1] += t1; cs[2] += t2; cs[3] += t3;
    }

    // pair-combine 32-row col partials into 64-row blocks via cscr
    const int pi = (wm >> 1) * 2 + wn;
    if ((wm & 1) == 1 && lg == 0) {
#pragma unroll
      for (int fn = 0; fn < 4; ++fn)
        cscr[pi * 64 + fn * 16 + lr] = make_float2(cm[fn], cs[fn]);
    }
    __syncthreads();
    if ((wm & 1) == 0 && lg == 0) {
      const int cblk = tm * 2 + (wm >> 1);
#pragma unroll
      for (int fn = 0; fn < 4; ++fn) {
        float2 o = cscr[pi * 64 + fn * 16 + lr];
        float M = fmaxf(cm[fn], o.x);
        float S = cs[fn] * fexp2(cm[fn] - M) + o.y * fexp2(o.x - M);
        colp[(size_t)cblk * NN + (cbase + fn * 16 + lr)] = make_float2(M, S);
      }
    }
  };

  __syncthreads();   // A + B(t1) staged

  // ---- tile 1 compute ----
  f32x4 acc[2][4] = {};
#pragma unroll
  for (int ks = 0; ks < 4; ++ks) {
    fragAB av[2], bv[4];
#pragma unroll
    for (int f = 0; f < 2; ++f)
      av[f] = *reinterpret_cast<const fragAB*>(
          &As[(wm * 32 + f * 16 + lr) * 128 + (((ks * 4 + lg) ^ lr) * 8)]);
#pragma unroll
    for (int f = 0; f < 4; ++f)
      bv[f] = *reinterpret_cast<const fragAB*>(
          &Bs[(wn * 64 + f * 16 + lr) * 128 + (((ks * 4 + lg) ^ lr) * 8)]);
#pragma unroll
    for (int fm = 0; fm < 2; ++fm)
#pragma unroll
      for (int fn = 0; fn < 4; ++fn)
        acc[fm][fn] = __builtin_amdgcn_mfma_f32_16x16x32_bf16(av[fm], bv[fn], acc[fm][fn], 0, 0, 0);
  }

  __syncthreads();   // all waves done reading B(t1)

  // ---- issue B(tile 2) staging; lands during tile-1 epilogue ----
  {
    const ushort* gB2 = Tb + (size_t)(tnp * 256 + 128 + trow) * EE + scol;
#pragma unroll
    for (int i = 0; i < 4; ++i)
      __builtin_amdgcn_global_load_lds((gvoid*)(gB2 + (size_t)i * 32 * EE),
          (lvoid*)((char*)Bs + i * 8192 + wid * 1024), 16, 0, 0);
  }

  epilogue(acc, tnp * 2);

  __syncthreads();   // B(t2) landed (barrier drains vmcnt)

  // ---- tile 2 compute (A re-read from still-live As) ----
  f32x4 acc2[2][4] = {};
#pragma unroll
  for (int ks = 0; ks < 4; ++ks) {
    fragAB av[2], bv[4];
#pragma unroll
    for (int f = 0; f < 2; ++f)
      av[f] = *reinterpret_cast<const fragAB*>(
          &As[(wm * 32 + f * 16 + lr) * 128 + (((ks * 4 + lg) ^ lr) * 8)]);
#pragma unroll
    for (int f = 0; f < 4; ++f)
      bv[f] = *reinterpret_cast<const fragAB*>(
          &Bs[(wn * 64 + f * 16 + lr) * 128 + (((ks * 4 + lg) ^ lr) * 8)]);
#pragma unroll
    for (int fm = 0; fm < 2; ++fm)
#pragma unroll
      for (int fn = 0; fn < 4; ++fn)
        acc2[fm][fn] = __builtin_amdgcn_mfma_f32_16x16x32_bf16(av[fm], bv[fn], acc2[fm][fn], 0, 0, 0);
  }

  epilogue(acc2, tnp * 2 + 1);
}

// WG handles 32 samples: stage [128 blocks][32 samples] slab through padded LDS
// (coalesced global reads), 8 threads per sample merge 128 partials in 2 passes.
__global__ __launch_bounds__(256) void
lsl_merge_kernel(const float2* __restrict__ rowp, const float2* __restrict__ colp,
                 const float* __restrict__ diag, float* __restrict__ bsum) {
  __shared__ float2 sl[128 * 33];
  __shared__ float2 red[32][8];
  const int tid = threadIdx.x;
  const int ibase = blockIdx.x * 32;
  const int s = tid & 31, p = tid >> 5;

  float lse0 = 0.f, lse1 = 0.f;
#pragma unroll
  for (int pass = 0; pass < 2; ++pass) {
    const float2* __restrict__ src = pass ? colp : rowp;
#pragma unroll
    for (int k = 0; k < 16; ++k) {
      int L = tid + k * 256;
      int b = L >> 5, di = L & 31;
      sl[b * 33 + di] = src[(size_t)b * NN + ibase + di];
    }
    __syncthreads();
    float m = SENT;
#pragma unroll
    for (int k = 0; k < 16; ++k) m = fmaxf(m, sl[(p * 16 + k) * 33 + s].x);
    float sum = 0.f;
#pragma unroll
    for (int k = 0; k < 16; ++k) {
      float2 v = sl[(p * 16 + k) * 33 + s];
      sum += v.y * fexp2(v.x - m);
    }
    red[s][p] = make_float2(m, sum);
    __syncthreads();
    if (p == 0) {
      float M = SENT;
#pragma unroll
      for (int k = 0; k < 8; ++k) M = fmaxf(M, red[s][k].x);
      float S = 0.f;
#pragma unroll
      for (int k = 0; k < 8; ++k) S += red[s][k].y * fexp2(red[s][k].x - M);
      if (pass == 0) lse0 = M + flog2(S); else lse1 = M + flog2(S);
    }
    __syncthreads();
  }

  if (tid < 32) {
    float loss = lse0 + lse1 - 2.f * diag[ibase + tid];   // log2 units
#pragma unroll
    for (int d = 1; d < 32; d <<= 1) loss += __shfl_xor(loss, d);
    if (tid == 0) bsum[blockIdx.x] = loss;
  }
}

__global__ __launch_bounds__(256) void
lsl_final_kernel(const float* __restrict__ bsum, float* __restrict__ out) {
  float v = bsum[threadIdx.x];
#pragma unroll
  for (int d = 1; d < 64; d <<= 1) v += __shfl_xor(v, d);
  __shared__ float l4[4];
  if ((threadIdx.x & 63) == 0) l4[threadIdx.x >> 6] = v;
  __syncthreads();
  if (threadIdx.x == 0) out[0] = (l4[0] + l4[1] + l4[2] + l4[3]) * (LN2 / (float)NN);
}

extern "C" void kernel_launch(void* const* d_in, const int* in_sizes, int n_in,
                              void* d_out, int out_size, void* d_ws, size_t ws_size,
                              hipStream_t stream) {
  const float* A = (const float*)d_in[0];
  const float* T = (const float*)d_in[1];
  const int* fids = (const int*)d_in[2];
  float* out = (float*)d_out;
  char* ws = (char*)d_ws;

  // ws: Ab 2MB | Tb 2MB | diag 32KB | rowp 8MB | colp 8MB | bsum 1KB
  size_t off = 0;
  ushort* Ab  = (ushort*)(ws + off); off += (size_t)NN * EE * 2;
  ushort* Tb  = (ushort*)(ws + off); off += (size_t)NN * EE * 2;
  float* diag = (float*)(ws + off);  off += (size_t)NN * 4;
  float2* rowp = (float2*)(ws + off); off += (size_t)NN * 128 * 8;
  float2* colp = (float2*)(ws + off); off += (size_t)NN * 128 * 8;
  float* bsum = (float*)(ws + off);  off += 1024;

  hipLaunchKernelGGL(lsl_cvt_kernel, dim3(NN * EE / 4 / 256), dim3(256), 0, stream, A, T, Ab, Tb, diag);
  hipLaunchKernelGGL(lsl_tile_kernel, dim3(2048), dim3(512), 0, stream, Ab, Tb, fids, rowp, colp);
  hipLaunchKernelGGL(lsl_merge_kernel, dim3(NN / 32), dim3(256), 0, stream, rowp, colp, diag, bsum);
  hipLaunchKernelGGL(lsl_final_kernel, dim3(1), dim3(256), 0, stream, bsum, out);
}

// Round 19
// 60.825 us; speedup vs baseline: 1.0629x; 1.0147x over previous
//
#include <hip/hip_runtime.h>
#include <hip/hip_bf16.h>
#include <math.h>

#define NN 8192
#define EE 128

static constexpr float INV_T = 1.0f / 0.07f;
static constexpr float LOG2E = 1.4426950408889634f;
static constexpr float LN2   = 0.6931471805599453f;
static constexpr float SENT  = -3.0e38f;

typedef __attribute__((ext_vector_type(8))) short fragAB;   // 8 bf16
typedef __attribute__((ext_vector_type(4))) float f32x4;
typedef const __attribute__((address_space(1))) void gvoid;
typedef __attribute__((address_space(3))) void lvoid;

__device__ inline float fexp2(float x) { float r; asm("v_exp_f32 %0, %1" : "=v"(r) : "v"(x)); return r; }
__device__ inline float flog2(float x) { float r; asm("v_log_f32 %0, %1" : "=v"(r) : "v"(x)); return r; }

template<int CTRL>
__device__ inline float dpp_f(float x) {
  return __builtin_bit_cast(float,
      __builtin_amdgcn_update_dpp(0, __builtin_bit_cast(int, x), CTRL, 0xf, 0xf, true));
}
__device__ inline float red16_max(float x) {
  x = fmaxf(x, dpp_f<0xB1>(x));    // quad_perm [1,0,3,2]
  x = fmaxf(x, dpp_f<0x4E>(x));    // quad_perm [2,3,0,1]
  x = fmaxf(x, dpp_f<0x141>(x));   // row_half_mirror
  x = fmaxf(x, dpp_f<0x140>(x));   // row_mirror
  return x;
}
__device__ inline float red16_add(float x) {
  x += dpp_f<0xB1>(x); x += dpp_f<0x4E>(x); x += dpp_f<0x141>(x); x += dpp_f<0x140>(x);
  return x;
}

__device__ inline ushort f32_to_bf16_bits(float x) {
  union { float f; unsigned u; } c; c.f = x;
  unsigned u = c.u;
  u += 0x7fffu + ((u >> 16) & 1u);   // RNE
  return (ushort)(u >> 16);
}

// fp32 -> bf16 (A pre-scaled by 1/temp*log2e so scores are log2-domain),
// plus exact fp32 diagonal dot products (log2 units).
__global__ void lsl_cvt_kernel(const float* __restrict__ A, const float* __restrict__ T,
                               ushort* __restrict__ Ab, ushort* __restrict__ Tb,
                               float* __restrict__ diag) {
  const int t = blockIdx.x * 256 + threadIdx.x;
  const int i = t * 4;
  float4 a = *reinterpret_cast<const float4*>(A + i);
  float4 tt = *reinterpret_cast<const float4*>(T + i);
  ushort4 oa, ot;
  const float SC = INV_T * LOG2E;
  oa.x = f32_to_bf16_bits(a.x * SC); oa.y = f32_to_bf16_bits(a.y * SC);
  oa.z = f32_to_bf16_bits(a.z * SC); oa.w = f32_to_bf16_bits(a.w * SC);
  ot.x = f32_to_bf16_bits(tt.x); ot.y = f32_to_bf16_bits(tt.y);
  ot.z = f32_to_bf16_bits(tt.z); ot.w = f32_to_bf16_bits(tt.w);
  *reinterpret_cast<ushort4*>(Ab + i) = oa;
  *reinterpret_cast<ushort4*>(Tb + i) = ot;

  float pd = a.x * tt.x + a.y * tt.y + a.z * tt.z + a.w * tt.w;
  pd += __shfl_xor(pd, 1); pd += __shfl_xor(pd, 2); pd += __shfl_xor(pd, 4);
  pd += __shfl_xor(pd, 8); pd += __shfl_xor(pd, 16);
  if ((threadIdx.x & 31) == 0) diag[i >> 7] = pd * (INV_T * LOG2E);   // log2 units
}

// WG = one 128-row band x TWO adjacent 128-col tiles (tn = 2*tnp, 2*tnp+1).
// 512 threads = 8 waves in 4x2 (32 rows x 64 cols each per tile). A staged
// once; B single-buffered, re-staged for tile 2 with the gload_lds burst
// issued before tile 1's epilogue. Barrier ledger (4 per WG):
//   S0: A+B1 staged.  S1: all waves done reading B(t1); then B2 issued.
//   S2 (inside ep1): cscr[0] writes visible AND, because each wave drains
//       its own vmcnt before s_barrier and all B2 loads were issued pre-ep1,
//       Bs(t2) is fully written -> t2 compute may start right after ep1.
//   S3 (inside ep2): cscr[1] writes visible.
// cscr is PING-PONGED per tile parity so ep2's writes can't race ep1's
// pair-combine reads (the reason the old 5th barrier existed).
// XOR-swizzled LDS (linear dest + pre-swizzled global source, same XOR on
// read). Cross-lane strictly __shfl_xor/DPP (permlane32_swap retired:
// 3 deterministic failures — R11/R14/R17).
__global__ __launch_bounds__(512, 4) void
lsl_tile_kernel(const ushort* __restrict__ Ab, const ushort* __restrict__ Tb,
                const int* __restrict__ fids,
                float2* __restrict__ rowp, float2* __restrict__ colp) {
  __shared__ ushort As[128 * 128];
  __shared__ ushort Bs[128 * 128];
  __shared__ float2 cscr[2][4 * 64];   // ping-pong per tile parity

  const int bid = blockIdx.x;
  const int swz = (bid & 7) * 256 + (bid >> 3);   // bijective XCD chunking (2048 WGs)
  const int tm = swz >> 5, tnp = swz & 31;
  const int tid = threadIdx.x;
  const int lane = tid & 63;
  const int wid  = tid >> 6;          // 0..7
  const int wm = wid >> 1;            // 0..3 (32-row band)
  const int wn = wid & 1;             // 0..1 (64-col band)
  const int rbase = tm * 128 + wm * 32;
  const int lr = lane & 15, lg = lane >> 4;

  // staging geometry (shared by A and both B tiles)
  const int trow = tid >> 4;                       // 0..31
  const int scol = ((tid & 15) ^ (trow & 15)) * 8;

  // ---- stage A (shared) + B(tile 1) ----
  {
    const ushort* gA = Ab + (size_t)(tm * 128 + trow) * EE + scol;
    const ushort* gB = Tb + (size_t)(tnp * 256 + trow) * EE + scol;
#pragma unroll
    for (int i = 0; i < 4; ++i)
      __builtin_amdgcn_global_load_lds((gvoid*)(gA + (size_t)i * 32 * EE),
          (lvoid*)((char*)As + i * 8192 + wid * 1024), 16, 0, 0);
#pragma unroll
    for (int i = 0; i < 4; ++i)
      __builtin_amdgcn_global_load_lds((gvoid*)(gB + (size_t)i * 32 * EE),
          (lvoid*)((char*)Bs + i * 8192 + wid * 1024), 16, 0, 0);
  }

  // row fids (shared by both tiles)
  int fr[2][4];
#pragma unroll
  for (int fm = 0; fm < 2; ++fm) {
    int4 v4 = *reinterpret_cast<const int4*>(fids + rbase + fm * 16 + lg * 4);
    fr[fm][0] = v4.x; fr[fm][1] = v4.y; fr[fm][2] = v4.z; fr[fm][3] = v4.w;
  }

  // epilogue for one computed 32x64 sub-tile; cbuf = cscr parity buffer
  auto epilogue = [&](f32x4 (&acc)[2][4], int tn, int cbuf) {
    const int cbase = tn * 128 + wn * 64;
    int fc[4];
#pragma unroll
    for (int fn = 0; fn < 4; ++fn) fc[fn] = fids[cbase + fn * 16 + lr];

    // read-once sweep: acc -> masked VGPR copies. Diagonal crosses this
    // 32x64 sub-tile when tm==tn and (wm>>1)==wn; then row==col <=>
    // fn == (wm&1)*2+fm and lr == lg*4+r.
    float e[2][4][4];
    const bool dt = (tm == tn) && ((wm >> 1) == wn);
    const int dfb = (wm & 1) * 2;
#pragma unroll
    for (int fm = 0; fm < 2; ++fm)
#pragma unroll
      for (int fn = 0; fn < 4; ++fn)
#pragma unroll
        for (int r = 0; r < 4; ++r) {
          float v = acc[fm][fn][r];
          bool keep = (fr[fm][r] != fc[fn]) || (dt && fn == dfb + fm && lr == lg * 4 + r);
          e[fm][fn][r] = keep ? v : SENT;
        }

    // row pass, stage-major
    float rm[2][4];
#pragma unroll
    for (int fm = 0; fm < 2; ++fm)
#pragma unroll
      for (int r = 0; r < 4; ++r)
        rm[fm][r] = fmaxf(fmaxf(e[fm][0][r], e[fm][1][r]),
                          fmaxf(e[fm][2][r], e[fm][3][r]));
#pragma unroll
    for (int fm = 0; fm < 2; ++fm)
#pragma unroll
      for (int r = 0; r < 4; ++r)
        rm[fm][r] = red16_max(rm[fm][r]);

    float rs[2][4];
#pragma unroll
    for (int fm = 0; fm < 2; ++fm)
#pragma unroll
      for (int r = 0; r < 4; ++r)
        rs[fm][r] = (fexp2(e[fm][0][r] - rm[fm][r]) + fexp2(e[fm][1][r] - rm[fm][r]))
                  + (fexp2(e[fm][2][r] - rm[fm][r]) + fexp2(e[fm][3][r] - rm[fm][r]));
#pragma unroll
    for (int fm = 0; fm < 2; ++fm)
#pragma unroll
      for (int r = 0; r < 4; ++r)
        rs[fm][r] = red16_add(rs[fm][r]);

    const int rblk = tn * 2 + wn;
    if (lr == 0) {
#pragma unroll
      for (int fm = 0; fm < 2; ++fm)
#pragma unroll
        for (int r = 0; r < 4; ++r)
          rowp[(size_t)rblk * NN + (rbase + fm * 16 + lg * 4 + r)] = make_float2(rm[fm][r], rs[fm][r]);
    }

    // col pass over this wave's 32 rows
    float cm[4];
#pragma unroll
    for (int fn = 0; fn < 4; ++fn) {
      float m0 = fmaxf(fmaxf(e[0][fn][0], e[0][fn][1]), fmaxf(e[0][fn][2], e[0][fn][3]));
      float m1 = fmaxf(fmaxf(e[1][fn][0], e[1][fn][1]), fmaxf(e[1][fn][2], e[1][fn][3]));
      cm[fn] = fmaxf(m0, m1);
    }
    {
      float t0 = __shfl_xor(cm[0], 16), t1 = __shfl_xor(cm[1], 16),
            t2 = __shfl_xor(cm[2], 16), t3 = __shfl_xor(cm[3], 16);
      cm[0] = fmaxf(cm[0], t0); cm[1] = fmaxf(cm[1], t1);
      cm[2] = fmaxf(cm[2], t2); cm[3] = fmaxf(cm[3], t3);
      t0 = __shfl_xor(cm[0], 32); t1 = __shfl_xor(cm[1], 32);
      t2 = __shfl_xor(cm[2], 32); t3 = __shfl_xor(cm[3], 32);
      cm[0] = fmaxf(cm[0], t0); cm[1] = fmaxf(cm[1], t1);
      cm[2] = fmaxf(cm[2], t2); cm[3] = fmaxf(cm[3], t3);
    }
    float cs[4];
#pragma unroll
    for (int fn = 0; fn < 4; ++fn) {
      float s0 = (fexp2(e[0][fn][0] - cm[fn]) + fexp2(e[0][fn][1] - cm[fn]))
               + (fexp2(e[0][fn][2] - cm[fn]) + fexp2(e[0][fn][3] - cm[fn]));
      float s1 = (fexp2(e[1][fn][0] - cm[fn]) + fexp2(e[1][fn][1] - cm[fn]))
               + (fexp2(e[1][fn][2] - cm[fn]) + fexp2(e[1][fn][3] - cm[fn]));
      cs[fn] = s0 + s1;
    }
    {
      float t0 = __shfl_xor(cs[0], 16), t1 = __shfl_xor(cs[1], 16),
            t2 = __shfl_xor(cs[2], 16), t3 = __shfl_xor(cs[3], 16);
      cs[0] += t0; cs[1] += t1; cs[2] += t2; cs[3] += t3;
      t0 = __shfl_xor(cs[0], 32); t1 = __shfl_xor(cs[1], 32);
      t2 = __shfl_xor(cs[2], 32); t3 = __shfl_xor(cs[3], 32);
      cs[0] += t0; cs[1] += t1; cs[2] += t2; cs[3] += t3;
    }

    // pair-combine 32-row col partials into 64-row blocks via cscr[cbuf]
    const int pi = (wm >> 1) * 2 + wn;
    if ((wm & 1) == 1 && lg == 0) {
#pragma unroll
      for (int fn = 0; fn < 4; ++fn)
        cscr[cbuf][pi * 64 + fn * 16 + lr] = make_float2(cm[fn], cs[fn]);
    }
    __syncthreads();   // cscr visible; also drains this tile's B-prefetch
    if ((wm & 1) == 0 && lg == 0) {
      const int cblk = tm * 2 + (wm >> 1);
#pragma unroll
      for (int fn = 0; fn < 4; ++fn) {
        float2 o = cscr[cbuf][pi * 64 + fn * 16 + lr];
        float M = fmaxf(cm[fn], o.x);
        float S = cs[fn] * fexp2(cm[fn] - M) + o.y * fexp2(o.x - M);
        colp[(size_t)cblk * NN + (cbase + fn * 16 + lr)] = make_float2(M, S);
      }
    }
  };

  __syncthreads();   // S0: A + B(t1) staged

  // ---- tile 1 compute ----
  f32x4 acc[2][4] = {};
#pragma unroll
  for (int ks = 0; ks < 4; ++ks) {
    fragAB av[2], bv[4];
#pragma unroll
    for (int f = 0; f < 2; ++f)
      av[f] = *reinterpret_cast<const fragAB*>(
          &As[(wm * 32 + f * 16 + lr) * 128 + (((ks * 4 + lg) ^ lr) * 8)]);
#pragma unroll
    for (int f = 0; f < 4; ++f)
      bv[f] = *reinterpret_cast<const fragAB*>(
          &Bs[(wn * 64 + f * 16 + lr) * 128 + (((ks * 4 + lg) ^ lr) * 8)]);
#pragma unroll
    for (int fm = 0; fm < 2; ++fm)
#pragma unroll
      for (int fn = 0; fn < 4; ++fn)
        acc[fm][fn] = __builtin_amdgcn_mfma_f32_16x16x32_bf16(av[fm], bv[fn], acc[fm][fn], 0, 0, 0);
  }

  __syncthreads();   // S1: all waves done reading B(t1)

  // ---- issue B(tile 2) staging; lands by ep1's internal barrier ----
  {
    const ushort* gB2 = Tb + (size_t)(tnp * 256 + 128 + trow) * EE + scol;
#pragma unroll
    for (int i = 0; i < 4; ++i)
      __builtin_amdgcn_global_load_lds((gvoid*)(gB2 + (size_t)i * 32 * EE),
          (lvoid*)((char*)Bs + i * 8192 + wid * 1024), 16, 0, 0);
  }

  epilogue(acc, tnp * 2, 0);   // S2 inside: cscr[0] + B(t2) both settled

  // ---- tile 2 compute (no extra barrier needed; see ledger above) ----
  f32x4 acc2[2][4] = {};
#pragma unroll
  for (int ks = 0; ks < 4; ++ks) {
    fragAB av[2], bv[4];
#pragma unroll
    for (int f = 0; f < 2; ++f)
      av[f] = *reinterpret_cast<const fragAB*>(
          &As[(wm * 32 + f * 16 + lr) * 128 + (((ks * 4 + lg) ^ lr) * 8)]);
#pragma unroll
    for (int f = 0; f < 4; ++f)
      bv[f] = *reinterpret_cast<const fragAB*>(
          &Bs[(wn * 64 + f * 16 + lr) * 128 + (((ks * 4 + lg) ^ lr) * 8)]);
#pragma unroll
    for (int fm = 0; fm < 2; ++fm)
#pragma unroll
      for (int fn = 0; fn < 4; ++fn)
        acc2[fm][fn] = __builtin_amdgcn_mfma_f32_16x16x32_bf16(av[fm], bv[fn], acc2[fm][fn], 0, 0, 0);
  }

  epilogue(acc2, tnp * 2 + 1, 1);   // S3 inside
}

// WG handles 32 samples: stage [128 blocks][32 samples] slab through padded LDS
// (coalesced global reads), 8 threads per sample merge 128 partials in 2 passes.
__global__ __launch_bounds__(256) void
lsl_merge_kernel(const float2* __restrict__ rowp, const float2* __restrict__ colp,
                 const float* __restrict__ diag, float* __restrict__ bsum) {
  __shared__ float2 sl[128 * 33];
  __shared__ float2 red[32][8];
  const int tid = threadIdx.x;
  const int ibase = blockIdx.x * 32;
  const int s = tid & 31, p = tid >> 5;

  float lse0 = 0.f, lse1 = 0.f;
#pragma unroll
  for (int pass = 0; pass < 2; ++pass) {
    const float2* __restrict__ src = pass ? colp : rowp;
#pragma unroll
    for (int k = 0; k < 16; ++k) {
      int L = tid + k * 256;
      int b = L >> 5, di = L & 31;
      sl[b * 33 + di] = src[(size_t)b * NN + ibase + di];
    }
    __syncthreads();
    float m = SENT;
#pragma unroll
    for (int k = 0; k < 16; ++k) m = fmaxf(m, sl[(p * 16 + k) * 33 + s].x);
    float sum = 0.f;
#pragma unroll
    for (int k = 0; k < 16; ++k) {
      float2 v = sl[(p * 16 + k) * 33 + s];
      sum += v.y * fexp2(v.x - m);
    }
    red[s][p] = make_float2(m, sum);
    __syncthreads();
    if (p == 0) {
      float M = SENT;
#pragma unroll
      for (int k = 0; k < 8; ++k) M = fmaxf(M, red[s][k].x);
      float S = 0.f;
#pragma unroll
      for (int k = 0; k < 8; ++k) S += red[s][k].y * fexp2(red[s][k].x - M);
      if (pass == 0) lse0 = M + flog2(S); else lse1 = M + flog2(S);
    }
    __syncthreads();
  }

  if (tid < 32) {
    float loss = lse0 + lse1 - 2.f * diag[ibase + tid];   // log2 units
#pragma unroll
    for (int d = 1; d < 32; d <<= 1) loss += __shfl_xor(loss, d);
    if (tid == 0) bsum[blockIdx.x] = loss;
  }
}

__global__ __launch_bounds__(256) void
lsl_final_kernel(const float* __restrict__ bsum, float* __restrict__ out) {
  float v = bsum[threadIdx.x];
#pragma unroll
  for (int d = 1; d < 64; d <<= 1) v += __shfl_xor(v, d);
  __shared__ float l4[4];
  if ((threadIdx.x & 63) == 0) l4[threadIdx.x >> 6] = v;
  __syncthreads();
  if (threadIdx.x == 0) out[0] = (l4[0] + l4[1] + l4[2] + l4[3]) * (LN2 / (float)NN);
}

extern "C" void kernel_launch(void* const* d_in, const int* in_sizes, int n_in,
                              void* d_out, int out_size, void* d_ws, size_t ws_size,
                              hipStream_t stream) {
  const float* A = (const float*)d_in[0];
  const float* T = (const float*)d_in[1];
  const int* fids = (const int*)d_in[2];
  float* out = (float*)d_out;
  char* ws = (char*)d_ws;

  // ws: Ab 2MB | Tb 2MB | diag 32KB | rowp 8MB | colp 8MB | bsum 1KB
  size_t off = 0;
  ushort* Ab  = (ushort*)(ws + off); off += (size_t)NN * EE * 2;
  ushort* Tb  = (ushort*)(ws + off); off += (size_t)NN * EE * 2;
  float* diag = (float*)(ws + off);  off += (size_t)NN * 4;
  float2* rowp = (float2*)(ws + off); off += (size_t)NN * 128 * 8;
  float2* colp = (float2*)(ws + off); off += (size_t)NN * 128 * 8;
  float* bsum = (float*)(ws + off);  off += 1024;

  hipLaunchKernelGGL(lsl_cvt_kernel, dim3(NN * EE / 4 / 256), dim3(256), 0, stream, A, T, Ab, Tb, diag);
  hipLaunchKernelGGL(lsl_tile_kernel, dim3(2048), dim3(512), 0, stream, Ab, Tb, fids, rowp, colp);
  hipLaunchKernelGGL(lsl_merge_kernel, dim3(NN / 32), dim3(256), 0, stream, rowp, colp, diag, bsum);
  hipLaunchKernelGGL(lsl_final_kernel, dim3(1), dim3(256), 0, stream, bsum, out);
}